// Round 8
// baseline (543.155 us; speedup 1.0000x reference)
//
#include <hip/hip_runtime.h>

#define L_    160
#define D_    256
#define DP_   257
#define Q_    66049            // DP*DP
#define WTR_  66176            // WT rows alloc (>= Q_)
#define TBS_  260              // T1bias row stride (f32)
#define IJ_   25600

typedef unsigned short u16;
typedef unsigned int   u32;
typedef __attribute__((ext_vector_type(8))) short short8_t;  // 8 bf16 (4 VGPR)
typedef __attribute__((ext_vector_type(4))) float f32x4;     // acc frag

__device__ __forceinline__ float bf2f(u16 u){ union{u32 i; float f;} x; x.i=((u32)u)<<16; return x.f; }
__device__ __forceinline__ u16 f2bf(float f){ u32 u=__float_as_uint(f); return (u16)((u + 0x7FFFu + ((u>>16)&1u))>>16); }
__device__ __forceinline__ void gload16(const void* g, void* l){
    __builtin_amdgcn_global_load_lds((const __attribute__((address_space(1))) u32*)g,
                                     (__attribute__((address_space(3))) u32*)l, 16, 0, 0);
}

// ---------------- shared MFMA core: C[M][N] += A[M][K=256] * B[K][N] ----------------
// Single-buffered (m97 2-barrier structure), 36.9 KB LDS -> 4 blocks/CU for TLP overlap.
// Bank-conflict fix (rule #21): LDS stays linear; the per-lane GLOBAL source chunk is
// permuted ch ^= (row>>1)&3, and reads XOR the same way — the read-side XOR folds into
// a per-lane constant, so 16 lanes spread across all 8 bank-quads (2-way = free).
// Rows = [hi 512B | lo 512B]; split-bf16: 3 MFMAs per frag pair.
template<int MF,int NF>
__device__ __forceinline__ void gemm_core(
    const u16* Ahi, const u16* Alo, int aStrideB,
    const u16* Bhi, const u16* Blo, int bStrideB,
    unsigned char* smem, f32x4 (&acc)[MF][NF])
{
    constexpr int AB = 32*MF*64;               // bytes of one A array in LDS
    constexpr int BB = 32*NF*64;
    constexpr int SLOTS = (2*AB+2*BB)/4096;    // 16B chunks per thread per K-tile
    const int tid=threadIdx.x, lane=tid&63, wv=tid>>6;
    const int wm=wv>>1, wn=wv&1;

    const unsigned char* src[SLOTS];
    #pragma unroll
    for(int s=0;s<SLOTS;++s){
        int byte=(s*256+tid)*16;
        int local; const unsigned char* base; int strideB;
        if(byte<AB)            { local=byte;          base=(const unsigned char*)Ahi; strideB=aStrideB; }
        else if(byte<2*AB)     { local=byte-AB;       base=(const unsigned char*)Alo; strideB=aStrideB; }
        else if(byte<2*AB+BB)  { local=byte-2*AB;     base=(const unsigned char*)Bhi; strideB=bStrideB; }
        else                   { local=byte-2*AB-BB;  base=(const unsigned char*)Blo; strideB=bStrideB; }
        int row=local>>6, ch=(local>>4)&3;
        int chs=ch ^ ((row>>1)&3);             // source-permuted swizzle (same 64B line)
        src[s]=base + (size_t)row*strideB + chs*16;
    }
    const int kbsw=((lane>>4) ^ ((lane>>1)&3))*16;   // swizzled read column (per-lane const)
    for(int t=0;t<8;++t){
        #pragma unroll
        for(int s=0;s<SLOTS;++s){ gload16(src[s], smem + s*4096 + wv*1024); src[s]+=64; }
        __syncthreads();   // drains vmcnt(0) -> LDS ready
        short8_t ah[MF], al[MF], bh[NF], bl[NF];
        #pragma unroll
        for(int m=0;m<MF;++m){
            int row=wm*16*MF + m*16 + (lane&15);
            ah[m]=*(const short8_t*)(smem + row*64 + kbsw);
            al[m]=*(const short8_t*)(smem + AB + row*64 + kbsw);
        }
        #pragma unroll
        for(int nn=0;nn<NF;++nn){
            int row=wn*16*NF + nn*16 + (lane&15);
            bh[nn]=*(const short8_t*)(smem + 2*AB + row*64 + kbsw);
            bl[nn]=*(const short8_t*)(smem + 2*AB + BB + row*64 + kbsw);
        }
        #pragma unroll
        for(int m=0;m<MF;++m)
        #pragma unroll
        for(int nn=0;nn<NF;++nn){
            acc[m][nn]=__builtin_amdgcn_mfma_f32_16x16x32_bf16(ah[m],bh[nn],acc[m][nn],0,0,0);
            acc[m][nn]=__builtin_amdgcn_mfma_f32_16x16x32_bf16(ah[m],bl[nn],acc[m][nn],0,0,0);
            acc[m][nn]=__builtin_amdgcn_mfma_f32_16x16x32_bf16(al[m],bh[nn],acc[m][nn],0,0,0);
        }
        __syncthreads();
    }
}

// ---------- pre-pass: W[a][q=b*257+c] -> WT[r=c*257+b] rows [hi 256|lo 256] u16 ----------
__global__ __launch_bounds__(256) void k_splitWT(const float* __restrict__ W,
        u32* __restrict__ WT32)
{
    __shared__ float tile[64][130];
    const int tid=threadIdx.x;
    const int q0=blockIdx.x*64, a0=blockIdx.y*128;
    #pragma unroll
    for(int w=0;w<32;++w){                    // read 128a x 64q, q-coalesced
        int idx=w*256+tid;
        int ar=idx>>6, qc=idx&63;
        int q=q0+qc;
        tile[qc][ar] = (q<Q_) ? W[(size_t)(a0+ar)*Q_ + q] : 0.f;
    }
    __syncthreads();
    const int lane=tid&63, wv=tid>>6;
    #pragma unroll
    for(int w=0;w<16;++w){                    // per wave: one q-column, 64 a-pairs
        int rq=w*4+wv;
        int q=q0+rq;
        if(q<Q_){
            u32 b=(u32)q/257u, c=(u32)q-b*257u;
            size_t r=(size_t)c*257u+b;
            float2 v=*(const float2*)&tile[rq][2*lane];
            u16 h0=f2bf(v.x), h1=f2bf(v.y);
            u32* dst=WT32 + r*256 + (a0>>1) + lane;
            dst[0]   = (u32)h0 | ((u32)h1<<16);
            dst[128] = (u32)f2bf(v.x-bf2f(h0)) | ((u32)f2bf(v.y-bf2f(h1))<<16);
        }
    }
}

// ---------- pre-pass: split l1/l2/l3 rows -> [hi 256|lo 256] u16 rows ----------
__global__ __launch_bounds__(256) void k_split3(
        const float* __restrict__ l1, const float* __restrict__ l2, const float* __restrict__ l3,
        u32* __restrict__ o1, u32* __restrict__ o2, u32* __restrict__ o3)
{
    const int bid=blockIdx.x;
    const int which=bid/320, rp=bid%320;
    const float* in = which==0 ? l1 : (which==1 ? l2 : l3);
    u32* out = which==0 ? o1 : (which==1 ? o2 : o3);
    const int row=rp*2 + (threadIdx.x>>7);
    const int col2=threadIdx.x&127;
    float2 v=*(const float2*)&in[(size_t)row*256 + col2*2];
    u16 h0=f2bf(v.x), h1=f2bf(v.y);
    u16 g0=f2bf(v.x-bf2f(h0)), g1=f2bf(v.y-bf2f(h1));
    out[(size_t)row*256 + col2]       = (u32)h0 | ((u32)h1<<16);
    out[(size_t)row*256 + 128 + col2] = (u32)g0 | ((u32)g1<<16);
}

// ------- Stage 1 (all n): T1[n][i*257+c][b] = sum_a l1p[n,i,a]*W[a,b,c]; + T1bias -------
// 2068 blocks; bijective XCD-chunk remap (m204): the 4 n-blocks sharing one WT tile run
// consecutively on the SAME XCD -> WT L2-hot. newid = n + 4*y; y<514 main, y>=514 bias.
__global__ __launch_bounds__(256,4) void k_stage1(
    const u16* __restrict__ l1sAll, const u16* __restrict__ WT,
    const float* __restrict__ W,
    u16* __restrict__ T1all, float* __restrict__ T1biasAll)
{
    constexpr int MF=5, NF=4;
    __shared__ __attribute__((aligned(64))) unsigned char smem[(32*MF+32*NF)*128];
    const int tid=threadIdx.x, lane=tid&63, wv=tid>>6, wm=wv>>1, wn=wv&1;

    const int wg=blockIdx.x;
    const int qq=2068/8, rr=2068%8;                 // 258, 4
    const int xcd=wg&7, loc=wg>>3;
    const int newid = (xcd<rr) ? xcd*(qq+1)+loc : rr*(qq+1)+(xcd-rr)*qq+loc;
    const int n = newid & 3, y = newid >> 2;

    const u16* l1s   = l1sAll + (size_t)n*160*512;
    u16* T1          = T1all  + (size_t)n*160*257*512;
    float* T1bias    = T1biasAll + (size_t)n*160*TBS_;

    f32x4 acc[MF][NF];
    if(y<514){
        const int c=y>>1, b0=(y&1)*128;
        #pragma unroll
        for(int nn=0;nn<NF;++nn){
            int b=b0 + wn*64 + nn*16 + (lane&15);
            float v=W[(size_t)256*Q_ + (size_t)b*DP_ + c];          // bias row a=256
            #pragma unroll
            for(int m=0;m<MF;++m) acc[m][nn]=(f32x4){v,v,v,v};
        }
        const u16* Bh=WT + ((size_t)c*257 + b0)*512;
        gemm_core<MF,NF>(l1s, l1s+256, 1024, Bh, Bh+256, 1024, smem, acc);
        #pragma unroll
        for(int m=0;m<MF;++m){
            int iRow=wm*80 + m*16 + (lane>>4)*4;
            #pragma unroll
            for(int nn=0;nn<NF;++nn){
                int b=b0 + wn*64 + nn*16 + (lane&15);
                #pragma unroll
                for(int r=0;r<4;++r){
                    size_t rowb=((size_t)(iRow+r)*257 + c)*512;
                    float v=acc[m][nn][r];
                    u16 h=f2bf(v);
                    T1[rowb + b]       = h;
                    T1[rowb + 256 + b] = f2bf(v-bf2f(h));
                }
            }
        }
    } else {
        const int t=y-514;
        const int c0 = (t==0)?0:((t==1)?128:129);                   // overlap: identical values
        #pragma unroll
        for(int nn=0;nn<NF;++nn){
            int c=c0 + wn*64 + nn*16 + (lane&15);
            float v=W[(size_t)256*Q_ + (size_t)256*DP_ + c];        // W[256][256][c]
            #pragma unroll
            for(int m=0;m<MF;++m) acc[m][nn]=(f32x4){v,v,v,v};
        }
        const u16* Bh=WT + ((size_t)c0*257 + 256)*512;
        gemm_core<MF,NF>(l1s, l1s+256, 1024, Bh, Bh+256, 257*1024, smem, acc);
        #pragma unroll
        for(int m=0;m<MF;++m){
            int iRow=wm*80 + m*16 + (lane>>4)*4;
            #pragma unroll
            for(int nn=0;nn<NF;++nn){
                int c=c0 + wn*64 + nn*16 + (lane&15);
                #pragma unroll
                for(int r=0;r<4;++r)
                    T1bias[(size_t)(iRow+r)*TBS_ + c]=acc[m][nn][r];
            }
        }
    }
}

// ------- Stage 2 (n-pair p): T2[z][ij][c] = sum_b l2p[j,b]*T1[n][i*257+c][b]; + T2bias -------
// grid (3,160,2): n = 2p+z; c0 in {0,128,130}; c<256 split store, c==256 -> T2bias, 257 masked.
__global__ __launch_bounds__(256,4) void k_stage2(
    const u16* __restrict__ l2sAll, const u16* __restrict__ T1all,
    const float* __restrict__ T1biasAll,
    u16* __restrict__ T2dst, float* __restrict__ T2biasQuad, int p)
{
    constexpr int MF=5, NF=4;
    __shared__ __attribute__((aligned(64))) unsigned char smem[(32*MF+32*NF)*128];
    const int tid=threadIdx.x, lane=tid&63, wv=tid>>6, wm=wv>>1, wn=wv&1;
    const int x=blockIdx.x, i=blockIdx.y, z=blockIdx.z;
    const int n=p*2+z;
    const int c0 = (x==0)?0:((x==1)?128:130);

    const u16* l2s      = l2sAll + (size_t)n*160*512;
    const u16* T1       = T1all  + (size_t)n*160*257*512;
    const float* T1bias = T1biasAll + (size_t)n*160*TBS_;
    u16* T2             = T2dst + (size_t)z*IJ_*512;
    float* T2bias       = T2biasQuad + (size_t)n*IJ_;

    f32x4 acc[MF][NF];
    #pragma unroll
    for(int nn=0;nn<NF;++nn){
        int c=c0 + wn*64 + nn*16 + (lane&15);
        float v=(c<=256) ? T1bias[(size_t)i*TBS_ + c] : 0.f;
        #pragma unroll
        for(int m=0;m<MF;++m) acc[m][nn]=(f32x4){v,v,v,v};
    }
    const u16* Bh=T1 + ((size_t)i*257 + c0)*512;
    gemm_core<MF,NF>(l2s, l2s+256, 1024, Bh, Bh+256, 1024, smem, acc);

    #pragma unroll
    for(int m=0;m<MF;++m){
        int j0=wm*80 + m*16 + (lane>>4)*4;
        #pragma unroll
        for(int nn=0;nn<NF;++nn){
            int c=c0 + wn*64 + nn*16 + (lane&15);
            #pragma unroll
            for(int r=0;r<4;++r){
                int ij=i*L_ + j0 + r;
                float v=acc[m][nn][r];
                if(c<256){
                    size_t rowb=(size_t)ij*512;
                    u16 h=f2bf(v);
                    T2[rowb + c]       = h;
                    T2[rowb + 256 + c] = f2bf(v-bf2f(h));
                } else if(c==256){
                    T2bias[ij]=v;                                   // exact f32
                }
            }
        }
    }
}

// ------- Stage 3 (all n): out[n][ij][k] = sum_c T2[n][ij][c]*l3p[n,k,c] -------
// grid (200,4); n<2 -> T2p0 (WT alias), n>=2 -> T2p1 (T1[0..1] alias). 800 blocks
// at 4/CU -> all resident, no second round.
__global__ __launch_bounds__(256,4) void k_stage3(
    const u16* __restrict__ T2p0, const u16* __restrict__ T2p1,
    const float* __restrict__ T2biasQuad,
    const u16* __restrict__ l3sAll, float* __restrict__ outp)
{
    constexpr int MF=4, NF=5;
    __shared__ __attribute__((aligned(64))) unsigned char smem[(32*MF+32*NF)*128];
    const int tid=threadIdx.x, lane=tid&63, wv=tid>>6, wm=wv>>1, wn=wv&1;
    const int n=blockIdx.y;
    const int ij0=blockIdx.x*128;

    const u16*  T2  = (n<2) ? (T2p0 + (size_t)n*IJ_*512) : (T2p1 + (size_t)(n-2)*IJ_*512);
    const float* Tb = T2biasQuad + (size_t)n*IJ_;
    const u16*  Bh  = l3sAll + (size_t)n*160*512;
    float* out      = outp + (size_t)n*IJ_*L_;

    f32x4 acc[MF][NF];
    #pragma unroll
    for(int m=0;m<MF;++m){
        float v[4];
        #pragma unroll
        for(int r=0;r<4;++r)
            v[r]=Tb[ij0 + wm*64 + m*16 + (lane>>4)*4 + r];          // bias c=256
        #pragma unroll
        for(int nn=0;nn<NF;++nn) acc[m][nn]=(f32x4){v[0],v[1],v[2],v[3]};
    }

    const u16* Ah=T2 + (size_t)ij0*512;
    gemm_core<MF,NF>(Ah, Ah+256, 1024, Bh, Bh+256, 1024, smem, acc);

    #pragma unroll
    for(int m=0;m<MF;++m){
        #pragma unroll
        for(int nn=0;nn<NF;++nn){
            int k=wn*80 + nn*16 + (lane&15);
            #pragma unroll
            for(int r=0;r<4;++r){
                int ij=ij0 + wm*64 + m*16 + (lane>>4)*4 + r;
                out[(size_t)ij*L_ + k]=acc[m][nn][r];
            }
        }
    }
}

extern "C" void kernel_launch(void* const* d_in, const int* in_sizes, int n_in,
                              void* d_out, int out_size, void* d_ws, size_t ws_size,
                              hipStream_t stream) {
    const float* l1=(const float*)d_in[0];
    const float* l2=(const float*)d_in[1];
    const float* l3=(const float*)d_in[2];
    const float* W =(const float*)d_in[3];
    float* outp=(float*)d_out;
    (void)ws_size; (void)in_sizes; (void)n_in; (void)out_size;

    u16* p=(u16*)d_ws;
    u16* WT =p;  p+=(size_t)WTR_*512;          // 67.8 MB; dead after s1 -> T2p0 aliases
    u16* l1s=p;  p+=(size_t)640*512;
    u16* l2s=p;  p+=(size_t)640*512;
    u16* l3s=p;  p+=(size_t)640*512;
    u16* T1all=p; p+=(size_t)4*160*257*512 + 512;  // 168.4 MB (+1 row pad for c0=130 overread)
    float* T1biasAll=(float*)p; p+=(size_t)4*L_*TBS_*2;
    float* T2biasQuad=(float*)p; p+=(size_t)4*IJ_*2;
    u16* T2p0 = WT;                            // 52.4 MB inside WT's 67.8 MB (dead after s1)
    u16* T2p1 = T1all;                         // 52.4 MB over T1[n0..n1] (dead after s2a)

    k_splitWT<<<dim3(1033,2), 256, 0, stream>>>(W, (u32*)WT);
    k_split3<<<960, 256, 0, stream>>>(l1, l2, l3, (u32*)l1s, (u32*)l2s, (u32*)l3s);

    k_stage1<<<2068, 256, 0, stream>>>(l1s, WT, W, T1all, T1biasAll);

    // pair 0 (n=0,1): reads T1[0..1], writes T2p0 (WT region)
    k_stage2<<<dim3(3,160,2), 256, 0, stream>>>(l2s, T1all, T1biasAll, T2p0, T2biasQuad, 0);
    // pair 1 (n=2,3): reads T1[2..3], writes T2p1 (T1[0..1] region, now dead)
    k_stage2<<<dim3(3,160,2), 256, 0, stream>>>(l2s, T1all, T1biasAll, T2p1, T2biasQuad, 1);

    k_stage3<<<dim3(200,4), 256, 0, stream>>>(T2p0, T2p1, T2biasQuad, l3s, outp);
}

// Round 10
// 312.817 us; speedup vs baseline: 1.7363x; 1.7363x over previous
//
#include <hip/hip_runtime.h>

#define L_    160
#define D_    256
#define DP_   257
#define Q_    66049            // DP*DP
#define WTR_  66176            // WT rows alloc (>= Q_)
#define TBS_  260              // T1bias row stride (f32)
#define IJ_   25600

typedef unsigned short u16;
typedef unsigned int   u32;
typedef __attribute__((ext_vector_type(8))) short short8_t;  // 8 bf16 (4 VGPR)
typedef __attribute__((ext_vector_type(4))) float f32x4;     // acc frag

__device__ __forceinline__ float bf2f(u16 u){ union{u32 i; float f;} x; x.i=((u32)u)<<16; return x.f; }
__device__ __forceinline__ u16 f2bf(float f){ u32 u=__float_as_uint(f); return (u16)((u + 0x7FFFu + ((u>>16)&1u))>>16); }
__device__ __forceinline__ void gload16(const void* g, void* l){
    __builtin_amdgcn_global_load_lds((const __attribute__((address_space(1))) u32*)g,
                                     (__attribute__((address_space(3))) u32*)l, 16, 0, 0);
}

// ---------------- shared MFMA core: C[M][N] += A[M][K=256] * B[K][N] ----------------
// r6-measured structure: 2-phase dbuf, prefetch-before-compute, one barrier per K-step,
// setprio around MFMA, launch at 2 blocks/CU (write-combining stays intact — r8 lesson).
// AS/BS = 1 or 2 arrays per operand. Split rows = [hi 512B | lo 512B] (lo at +512B);
// single rows = 512B. Split-bf16 MFMA count: 2x2->3 (hh,hl,lh), 2x1->2, 1x2->2.
// Bank-conflict fix (rule #21, r8-verified): source chunk permuted ch^=(row>>1)&3,
// read column XOR folds into per-lane constant kbsw.
template<int MF,int NF,int AS,int BS>
__device__ __forceinline__ void gemm_core(
    const u16* A, int aStrideB,
    const u16* B, int bStrideB,
    unsigned char* smem, f32x4 (&acc)[MF][NF])
{
    constexpr int AB = 32*MF*64;               // bytes per A array per K-tile
    constexpr int BB = 32*NF*64;
    constexpr int ABYTES = AS*AB;
    constexpr int HALF = AS*AB + BS*BB;
    constexpr int SLOTS = HALF/4096;           // 16B chunks per thread per K-tile
    static_assert(SLOTS*4096 == HALF, "slot granularity");
    const int tid=threadIdx.x, lane=tid&63, wv=tid>>6;
    const int wm=wv>>1, wn=wv&1;

    const unsigned char* src[SLOTS];
    #pragma unroll
    for(int s=0;s<SLOTS;++s){
        int byte=(s*256+tid)*16;
        const unsigned char* base; int strideB, local, arrOfs;
        if(byte<ABYTES){ int arr=byte/AB; local=byte-arr*AB;
                         base=(const unsigned char*)A; strideB=aStrideB; arrOfs=arr*512; }
        else           { int b2=byte-ABYTES; int arr=b2/BB; local=b2-arr*BB;
                         base=(const unsigned char*)B; strideB=bStrideB; arrOfs=arr*512; }
        int row=local>>6, ch=(local>>4)&3;
        int chs=ch ^ ((row>>1)&3);             // source-permuted swizzle (same 64B line)
        src[s]=base + (size_t)row*strideB + arrOfs + chs*16;
    }

    // prologue: stage t=0 into half 0
    #pragma unroll
    for(int s=0;s<SLOTS;++s){ gload16(src[s], smem + s*4096 + wv*1024); src[s]+=64; }
    __syncthreads();

    const int kbsw=((lane>>4) ^ ((lane>>1)&3))*16;   // swizzled read column (per-lane const)
    #pragma unroll
    for(int t=0;t<8;++t){
        const unsigned char* cb = smem + (t&1)*HALF;
        if(t<7){                                   // prefetch t+1 into other half
            unsigned char* nb = smem + ((t+1)&1)*HALF;
            #pragma unroll
            for(int s=0;s<SLOTS;++s){ gload16(src[s], nb + s*4096 + wv*1024); src[s]+=64; }
        }
        short8_t ah[MF], bh[NF];
        short8_t al[AS==2?MF:1], bl[BS==2?NF:1];
        #pragma unroll
        for(int m=0;m<MF;++m){
            int row=wm*16*MF + m*16 + (lane&15);
            ah[m]=*(const short8_t*)(cb + row*64 + kbsw);
            if constexpr(AS==2) al[m]=*(const short8_t*)(cb + AB + row*64 + kbsw);
        }
        #pragma unroll
        for(int nn=0;nn<NF;++nn){
            int row=wn*16*NF + nn*16 + (lane&15);
            bh[nn]=*(const short8_t*)(cb + ABYTES + row*64 + kbsw);
            if constexpr(BS==2) bl[nn]=*(const short8_t*)(cb + ABYTES + BB + row*64 + kbsw);
        }
        __builtin_amdgcn_s_setprio(1);
        #pragma unroll
        for(int m=0;m<MF;++m)
        #pragma unroll
        for(int nn=0;nn<NF;++nn){
            acc[m][nn]=__builtin_amdgcn_mfma_f32_16x16x32_bf16(ah[m],bh[nn],acc[m][nn],0,0,0);
            if constexpr(AS==2 && BS==2){
                acc[m][nn]=__builtin_amdgcn_mfma_f32_16x16x32_bf16(ah[m],bl[nn],acc[m][nn],0,0,0);
                acc[m][nn]=__builtin_amdgcn_mfma_f32_16x16x32_bf16(al[m],bh[nn],acc[m][nn],0,0,0);
            } else if constexpr(AS==2){
                acc[m][nn]=__builtin_amdgcn_mfma_f32_16x16x32_bf16(al[m],bh[nn],acc[m][nn],0,0,0);
            } else if constexpr(BS==2){
                acc[m][nn]=__builtin_amdgcn_mfma_f32_16x16x32_bf16(ah[m],bl[nn],acc[m][nn],0,0,0);
            }
        }
        __builtin_amdgcn_s_setprio(0);
        __syncthreads();   // drains residual vmcnt of the prefetch; frees both halves
    }
}

// ---------- pre-pass: W[a][q=b*257+c] -> WT[r=c*257+b] rows [hi 256|lo 256] u16 ----------
__global__ __launch_bounds__(256) void k_splitWT(const float* __restrict__ W,
        u32* __restrict__ WT32)
{
    __shared__ float tile[64][130];
    const int tid=threadIdx.x;
    const int q0=blockIdx.x*64, a0=blockIdx.y*128;
    #pragma unroll
    for(int w=0;w<32;++w){                    // read 128a x 64q, q-coalesced
        int idx=w*256+tid;
        int ar=idx>>6, qc=idx&63;
        int q=q0+qc;
        tile[qc][ar] = (q<Q_) ? W[(size_t)(a0+ar)*Q_ + q] : 0.f;
    }
    __syncthreads();
    const int lane=tid&63, wv=tid>>6;
    #pragma unroll
    for(int w=0;w<16;++w){                    // per wave: one q-column, 64 a-pairs
        int rq=w*4+wv;
        int q=q0+rq;
        if(q<Q_){
            u32 b=(u32)q/257u, c=(u32)q-b*257u;
            size_t r=(size_t)c*257u+b;
            float2 v=*(const float2*)&tile[rq][2*lane];
            u16 h0=f2bf(v.x), h1=f2bf(v.y);
            u32* dst=WT32 + r*256 + (a0>>1) + lane;
            dst[0]   = (u32)h0 | ((u32)h1<<16);
            dst[128] = (u32)f2bf(v.x-bf2f(h0)) | ((u32)f2bf(v.y-bf2f(h1))<<16);
        }
    }
}

// ---------- pre-pass: split l1/l2/l3 rows -> [hi 256|lo 256] u16 rows ----------
__global__ __launch_bounds__(256) void k_split3(
        const float* __restrict__ l1, const float* __restrict__ l2, const float* __restrict__ l3,
        u32* __restrict__ o1, u32* __restrict__ o2, u32* __restrict__ o3)
{
    const int bid=blockIdx.x;
    const int which=bid/320, rp=bid%320;
    const float* in = which==0 ? l1 : (which==1 ? l2 : l3);
    u32* out = which==0 ? o1 : (which==1 ? o2 : o3);
    const int row=rp*2 + (threadIdx.x>>7);
    const int col2=threadIdx.x&127;
    float2 v=*(const float2*)&in[(size_t)row*256 + col2*2];
    u16 h0=f2bf(v.x), h1=f2bf(v.y);
    u16 g0=f2bf(v.x-bf2f(h0)), g1=f2bf(v.y-bf2f(h1));
    out[(size_t)row*256 + col2]       = (u32)h0 | ((u32)h1<<16);
    out[(size_t)row*256 + 128 + col2] = (u32)g0 | ((u32)g1<<16);
}

// ------- Stage 1 (all n): T1[n][i*257+c][b] = sum_a l1p[n,i,a]*W[a,b,c]; + T1bias -------
// A=l1 split x B=WT split (3-MFMA). T1 stored SINGLE bf16 (error budget: ~0.035 std
// into out, threshold 0.5). 2068 blocks; bijective XCD-chunk remap (m204).
__global__ __launch_bounds__(256,2) void k_stage1(
    const u16* __restrict__ l1sAll, const u16* __restrict__ WT,
    const float* __restrict__ W,
    u16* __restrict__ T1all, float* __restrict__ T1biasAll)
{
    constexpr int MF=5, NF=4;
    __shared__ __attribute__((aligned(64))) unsigned char smem[2*(2*32*MF+2*32*NF)*64];
    const int tid=threadIdx.x, lane=tid&63, wv=tid>>6, wm=wv>>1, wn=wv&1;

    const int wg=blockIdx.x;
    const int qq=2068/8, rr=2068%8;                 // 258, 4
    const int xcd=wg&7, loc=wg>>3;
    const int newid = (xcd<rr) ? xcd*(qq+1)+loc : rr*(qq+1)+(xcd-rr)*qq+loc;
    const int n = newid & 3, y = newid >> 2;

    const u16* l1s   = l1sAll + (size_t)n*160*512;
    u16* T1          = T1all  + (size_t)n*160*257*256;
    float* T1bias    = T1biasAll + (size_t)n*160*TBS_;

    f32x4 acc[MF][NF];
    if(y<514){
        const int c=y>>1, b0=(y&1)*128;
        #pragma unroll
        for(int nn=0;nn<NF;++nn){
            int b=b0 + wn*64 + nn*16 + (lane&15);
            float v=W[(size_t)256*Q_ + (size_t)b*DP_ + c];          // bias row a=256
            #pragma unroll
            for(int m=0;m<MF;++m) acc[m][nn]=(f32x4){v,v,v,v};
        }
        const u16* Bh=WT + ((size_t)c*257 + b0)*512;
        gemm_core<MF,NF,2,2>(l1s, 1024, Bh, 1024, smem, acc);
        #pragma unroll
        for(int m=0;m<MF;++m){
            int iRow=wm*80 + m*16 + (lane>>4)*4;
            #pragma unroll
            for(int nn=0;nn<NF;++nn){
                int b=b0 + wn*64 + nn*16 + (lane&15);
                #pragma unroll
                for(int r=0;r<4;++r){
                    size_t rowu=((size_t)(iRow+r)*257 + c)*256;
                    T1[rowu + b]=f2bf(acc[m][nn][r]);               // single bf16
                }
            }
        }
    } else {
        const int t=y-514;
        const int c0 = (t==0)?0:((t==1)?128:129);                   // overlap: identical values
        #pragma unroll
        for(int nn=0;nn<NF;++nn){
            int c=c0 + wn*64 + nn*16 + (lane&15);
            float v=W[(size_t)256*Q_ + (size_t)256*DP_ + c];        // W[256][256][c]
            #pragma unroll
            for(int m=0;m<MF;++m) acc[m][nn]=(f32x4){v,v,v,v};
        }
        const u16* Bh=WT + ((size_t)c0*257 + 256)*512;
        gemm_core<MF,NF,2,2>(l1s, 1024, Bh, 257*1024, smem, acc);
        #pragma unroll
        for(int m=0;m<MF;++m){
            int iRow=wm*80 + m*16 + (lane>>4)*4;
            #pragma unroll
            for(int nn=0;nn<NF;++nn){
                int c=c0 + wn*64 + nn*16 + (lane&15);
                #pragma unroll
                for(int r=0;r<4;++r)
                    T1bias[(size_t)(iRow+r)*TBS_ + c]=acc[m][nn][r];
            }
        }
    }
}

// ------- Stage 2 (all n): T2[n][ij][c] = sum_b l2p[j,b]*T1[n][i*257+c][b]; + T2bias -------
// A=l2 split x B=T1 single (2-MFMA). grid (3,160,4); c0 in {0,128,130};
// c<256 single-bf16 store, c==256 -> T2bias f32, c==257 masked.
__global__ __launch_bounds__(256,2) void k_stage2(
    const u16* __restrict__ l2sAll, const u16* __restrict__ T1all,
    const float* __restrict__ T1biasAll,
    u16* __restrict__ T2all, float* __restrict__ T2biasQuad)
{
    constexpr int MF=5, NF=4;
    __shared__ __attribute__((aligned(64))) unsigned char smem[2*(2*32*MF+32*NF)*64];
    const int tid=threadIdx.x, lane=tid&63, wv=tid>>6, wm=wv>>1, wn=wv&1;
    const int x=blockIdx.x, i=blockIdx.y, n=blockIdx.z;
    const int c0 = (x==0)?0:((x==1)?128:130);

    const u16* l2s      = l2sAll + (size_t)n*160*512;
    const u16* T1       = T1all  + (size_t)n*160*257*256;
    const float* T1bias = T1biasAll + (size_t)n*160*TBS_;
    u16* T2             = T2all + (size_t)n*IJ_*256;
    float* T2bias       = T2biasQuad + (size_t)n*IJ_;

    f32x4 acc[MF][NF];
    #pragma unroll
    for(int nn=0;nn<NF;++nn){
        int c=c0 + wn*64 + nn*16 + (lane&15);
        float v=(c<=256) ? T1bias[(size_t)i*TBS_ + c] : 0.f;
        #pragma unroll
        for(int m=0;m<MF;++m) acc[m][nn]=(f32x4){v,v,v,v};
    }
    const u16* Bh=T1 + ((size_t)i*257 + c0)*256;
    gemm_core<MF,NF,2,1>(l2s, 1024, Bh, 512, smem, acc);

    #pragma unroll
    for(int m=0;m<MF;++m){
        int j0=wm*80 + m*16 + (lane>>4)*4;
        #pragma unroll
        for(int nn=0;nn<NF;++nn){
            int c=c0 + wn*64 + nn*16 + (lane&15);
            #pragma unroll
            for(int r=0;r<4;++r){
                int ij=i*L_ + j0 + r;
                float v=acc[m][nn][r];
                if(c<256){
                    T2[(size_t)ij*256 + c]=f2bf(v);                 // single bf16
                } else if(c==256){
                    T2bias[ij]=v;                                   // exact f32
                }
            }
        }
    }
}

// ------- Stage 3 (all n): out[n][ij][k] = sum_c T2[n][ij][c]*l3p[n,k,c] -------
// A=T2 single x B=l3 split (2-MFMA). grid (200,4).
__global__ __launch_bounds__(256,2) void k_stage3(
    const u16* __restrict__ T2all, const float* __restrict__ T2biasQuad,
    const u16* __restrict__ l3sAll, float* __restrict__ outp)
{
    constexpr int MF=4, NF=5;
    __shared__ __attribute__((aligned(64))) unsigned char smem[2*(32*MF+2*32*NF)*64];
    const int tid=threadIdx.x, lane=tid&63, wv=tid>>6, wm=wv>>1, wn=wv&1;
    const int n=blockIdx.y;
    const int ij0=blockIdx.x*128;

    const u16*  T2  = T2all + (size_t)n*IJ_*256;
    const float* Tb = T2biasQuad + (size_t)n*IJ_;
    const u16*  Bh  = l3sAll + (size_t)n*160*512;
    float* out      = outp + (size_t)n*IJ_*L_;

    f32x4 acc[MF][NF];
    #pragma unroll
    for(int m=0;m<MF;++m){
        float v[4];
        #pragma unroll
        for(int r=0;r<4;++r)
            v[r]=Tb[ij0 + wm*64 + m*16 + (lane>>4)*4 + r];          // bias c=256
        #pragma unroll
        for(int nn=0;nn<NF;++nn) acc[m][nn]=(f32x4){v[0],v[1],v[2],v[3]};
    }

    const u16* Ah=T2 + (size_t)ij0*256;
    gemm_core<MF,NF,1,2>(Ah, 512, Bh, 1024, smem, acc);

    #pragma unroll
    for(int m=0;m<MF;++m){
        #pragma unroll
        for(int nn=0;nn<NF;++nn){
            int k=wn*80 + nn*16 + (lane&15);
            #pragma unroll
            for(int r=0;r<4;++r){
                int ij=ij0 + wm*64 + m*16 + (lane>>4)*4 + r;
                out[(size_t)ij*L_ + k]=acc[m][nn][r];
            }
        }
    }
}

extern "C" void kernel_launch(void* const* d_in, const int* in_sizes, int n_in,
                              void* d_out, int out_size, void* d_ws, size_t ws_size,
                              hipStream_t stream) {
    const float* l1=(const float*)d_in[0];
    const float* l2=(const float*)d_in[1];
    const float* l3=(const float*)d_in[2];
    const float* W =(const float*)d_in[3];
    float* outp=(float*)d_out;
    (void)ws_size; (void)in_sizes; (void)n_in; (void)out_size;

    u16* p=(u16*)d_ws;
    u16* WT =p;  p+=(size_t)WTR_*512;              // 67.8 MB (split hi|lo)
    u16* l1s=p;  p+=(size_t)640*512;
    u16* l2s=p;  p+=(size_t)640*512;
    u16* l3s=p;  p+=(size_t)640*512;
    u16* T1all=p; p+=(size_t)4*160*257*256 + 256;  // 84.2 MB single bf16 (+pad row)
    u16* T2all=p; p+=(size_t)4*IJ_*256;            // 52.4 MB single bf16
    float* T1biasAll=(float*)p; p+=(size_t)4*L_*TBS_*2;
    float* T2biasQuad=(float*)p; p+=(size_t)4*IJ_*2;

    k_splitWT<<<dim3(1033,2), 256, 0, stream>>>(W, (u32*)WT);
    k_split3<<<960, 256, 0, stream>>>(l1, l2, l3, (u32*)l1s, (u32*)l2s, (u32*)l3s);

    k_stage1<<<2068, 256, 0, stream>>>(l1s, WT, W, T1all, T1biasAll);
    k_stage2<<<dim3(3,160,4), 256, 0, stream>>>(l2s, T1all, T1biasAll, T2all, T2biasQuad);
    k_stage3<<<dim3(200,4), 256, 0, stream>>>(T2all, T2biasQuad, l3s, outp);
}